// Round 1
// baseline (739.235 us; speedup 1.0000x reference)
//
#include <hip/hip_runtime.h>
#include <hip/hip_bf16.h>

typedef unsigned short u16;
typedef __attribute__((ext_vector_type(4))) float f32x4;
typedef __attribute__((ext_vector_type(8))) short short8;
typedef __attribute__((ext_vector_type(4))) unsigned short u16x4;

// B=32, T=64, I=H=512, V=32000, G=4H=2048, M=T*B=2048
#define NB 32
#define NT 64
#define NK 512
#define NG 2048
#define NV 32000

static __device__ __forceinline__ u16 f2bf(float f) {
  union { float f; unsigned u; } v; v.f = f;
  unsigned r = v.u + 0x7FFFu + ((v.u >> 16) & 1u);
  return (u16)(r >> 16);
}

static __device__ __forceinline__ void gload_lds16(const void* g, void* l) {
  __builtin_amdgcn_global_load_lds(
      (const __attribute__((address_space(1))) unsigned int*)g,
      (__attribute__((address_space(3))) unsigned int*)l, 16, 0, 0);
}

// ---------------- prep: casts + transpose + zero c ----------------
__global__ void prep_kernel(const float* __restrict__ iseq, const float* __restrict__ h0,
                            const float* __restrict__ wih, const float* __restrict__ whh,
                            const float* __restrict__ wout,
                            u16* __restrict__ wout_bf, u16* __restrict__ wih_bf,
                            u16* __restrict__ whh_bf, u16* __restrict__ ax,
                            u16* __restrict__ h0bf, float* __restrict__ cbuf) {
  const int UW = 4096000;          // Wout: 16.384M elems /4
  const int UWI = 262144;          // Wih /4
  const int S0 = UW, S1 = S0 + UWI, S2 = S1 + UWI, S3 = S2 + UWI;
  const int S4 = S3 + 4096, S5 = S4 + 4096;
  int u = blockIdx.x * blockDim.x + threadIdx.x;
  int stride = gridDim.x * blockDim.x;
  for (; u < S5; u += stride) {
    if (u < S0) {
      int e = u * 4; f32x4 v = *(const f32x4*)(wout + e);
      u16x4 o; o[0]=f2bf(v[0]); o[1]=f2bf(v[1]); o[2]=f2bf(v[2]); o[3]=f2bf(v[3]);
      *(u16x4*)(wout_bf + e) = o;
    } else if (u < S1) {
      int e = (u - S0) * 4; f32x4 v = *(const f32x4*)(wih + e);
      u16x4 o; o[0]=f2bf(v[0]); o[1]=f2bf(v[1]); o[2]=f2bf(v[2]); o[3]=f2bf(v[3]);
      *(u16x4*)(wih_bf + e) = o;
    } else if (u < S2) {
      int e = (u - S1) * 4; f32x4 v = *(const f32x4*)(whh + e);
      u16x4 o; o[0]=f2bf(v[0]); o[1]=f2bf(v[1]); o[2]=f2bf(v[2]); o[3]=f2bf(v[3]);
      *(u16x4*)(whh_bf + e) = o;
    } else if (u < S3) {
      // A_x[m= t*32+b][k] = iseq[b][t][k]
      int e = (u - S2) * 4; int m = e >> 9; int k = e & 511;
      int b = m & 31; int t = m >> 5;
      f32x4 v = *(const f32x4*)(iseq + ((b * 64 + t) << 9) + k);
      u16x4 o; o[0]=f2bf(v[0]); o[1]=f2bf(v[1]); o[2]=f2bf(v[2]); o[3]=f2bf(v[3]);
      *(u16x4*)(ax + e) = o;
    } else if (u < S4) {
      int e = (u - S3) * 4; f32x4 v = *(const f32x4*)(h0 + e);
      u16x4 o; o[0]=f2bf(v[0]); o[1]=f2bf(v[1]); o[2]=f2bf(v[2]); o[3]=f2bf(v[3]);
      *(u16x4*)(h0bf + e) = o;
    } else {
      int e = (u - S4) * 4;
      f32x4 z = {0.f, 0.f, 0.f, 0.f};
      *(f32x4*)(cbuf + e) = z;
    }
  }
}

// ---------------- generic C = A*Bw^T + bias GEMM ----------------
// A: [2048][512] bf16 row-major, Bw: [N][512] bf16 row-major, C: [2048][N] f32
// tile 128x128, BK=64, 4 waves; global_load_lds(16B) with pre-swizzled source,
// XOR-swizzled ds_read_b128.
__global__ __launch_bounds__(256, 2) void gemm_bt(
    const u16* __restrict__ A, const u16* __restrict__ Bw,
    float* __restrict__ C, const float* __restrict__ bias1,
    const float* __restrict__ bias2, int N) {
  __shared__ u16 As[2][8192];
  __shared__ u16 Bs[2][8192];
  const int tid = threadIdx.x;
  const int w = tid >> 6, l = tid & 63;
  const int wr = w >> 1, wc = w & 1;
  const int tm = blockIdx.y * 128, tn = blockIdx.x * 128;

  f32x4 acc[4][4];
#pragma unroll
  for (int i = 0; i < 4; ++i)
#pragma unroll
    for (int j = 0; j < 4; ++j) acc[i][j] = (f32x4){0.f, 0.f, 0.f, 0.f};

  auto stage = [&](int buf, int kt) {
#pragma unroll
    for (int i = 0; i < 4; ++i) {
      int r = (w * 4 + i) * 8 + (l >> 3);
      int c16 = (l & 7) ^ (r & 7);  // pre-swizzled source column
      const u16* srca = A + (tm + r) * 512 + kt * 64 + c16 * 8;
      gload_lds16(srca, &As[buf][(w * 4 + i) * 512]);
      const u16* srcb = Bw + (tn + r) * 512 + kt * 64 + c16 * 8;
      gload_lds16(srcb, &Bs[buf][(w * 4 + i) * 512]);
    }
  };

  stage(0, 0);
  int buf = 0;
  for (int kt = 0; kt < 8; ++kt) {
    __syncthreads();  // drains vmcnt for buf's loads + barrier
    if (kt < 7) stage(buf ^ 1, kt + 1);
#pragma unroll
    for (int kk = 0; kk < 2; ++kk) {
      short8 af[4], bfr[4];
#pragma unroll
      for (int mi = 0; mi < 4; ++mi) {
        int row = wr * 64 + mi * 16 + (l & 15);
        int s = (kk * 4 + (l >> 4)) ^ (row & 7);
        af[mi] = *(const short8*)&As[buf][row * 64 + s * 8];
      }
#pragma unroll
      for (int ni = 0; ni < 4; ++ni) {
        int row = wc * 64 + ni * 16 + (l & 15);
        int s = (kk * 4 + (l >> 4)) ^ (row & 7);
        bfr[ni] = *(const short8*)&Bs[buf][row * 64 + s * 8];
      }
#pragma unroll
      for (int mi = 0; mi < 4; ++mi)
#pragma unroll
        for (int ni = 0; ni < 4; ++ni)
          acc[mi][ni] = __builtin_amdgcn_mfma_f32_16x16x32_bf16(
              af[mi], bfr[ni], acc[mi][ni], 0, 0, 0);
    }
    buf ^= 1;
  }

#pragma unroll
  for (int ni = 0; ni < 4; ++ni) {
    int gcol = tn + wc * 64 + ni * 16 + (l & 15);
    float bv = 0.f;
    if (bias1) bv += bias1[gcol];
    if (bias2) bv += bias2[gcol];
#pragma unroll
    for (int mi = 0; mi < 4; ++mi) {
      int grow0 = tm + wr * 64 + mi * 16 + ((l >> 4) << 2);
      f32x4 a = acc[mi][ni];
#pragma unroll
      for (int q = 0; q < 4; ++q) {
        C[(long long)(grow0 + q) * N + gcol] = a[q] + bv;
      }
    }
  }
}

// ---------------- one LSTM recurrence step ----------------
// 128 blocks x 64 threads. Block owns j0..j0+3 (4 h-columns) => 16 W_hh rows
// ({i,f,g,o} x 4j) as the MFMA N=16 tile. gates = h_{t-1} @ W_hh^T + xg[t].
__global__ __launch_bounds__(64, 1) void lstm_step(
    const u16* __restrict__ whh, const float* __restrict__ xg,
    float* __restrict__ cbuf, u16* __restrict__ h_all,
    const u16* __restrict__ h0bf, int t) {
  const int l = threadIdx.x;
  const int j0 = blockIdx.x * 4;
  const int c = l & 15;
  const int wrow = (c >> 2) * 512 + j0 + (c & 3);  // W_hh row == gate column
  const int ko = (l >> 4) * 8;

  short8 bfr[16];
  const u16* wp = whh + wrow * 512 + ko;
#pragma unroll
  for (int kt = 0; kt < 16; ++kt) bfr[kt] = *(const short8*)(wp + kt * 32);

  short8 af[2][16];
#pragma unroll
  for (int mt = 0; mt < 2; ++mt) {
    int b = mt * 16 + (l & 15);
    const u16* hp = (t == 0) ? (h0bf + b * 512)
                             : (h_all + (b * 64 + (t - 1)) * 512);
    hp += ko;
#pragma unroll
    for (int kt = 0; kt < 16; ++kt) af[mt][kt] = *(const short8*)(hp + kt * 32);
  }

  f32x4 acc[2];
  acc[0] = (f32x4){0.f, 0.f, 0.f, 0.f};
  acc[1] = (f32x4){0.f, 0.f, 0.f, 0.f};
#pragma unroll
  for (int kt = 0; kt < 16; ++kt) {
    acc[0] = __builtin_amdgcn_mfma_f32_16x16x32_bf16(af[0][kt], bfr[kt], acc[0], 0, 0, 0);
    acc[1] = __builtin_amdgcn_mfma_f32_16x16x32_bf16(af[1][kt], bfr[kt], acc[1], 0, 0, 0);
  }

  const int rq = (l >> 4) * 4;
  const int jj = l & 3;
#pragma unroll
  for (int mt = 0; mt < 2; ++mt) {
#pragma unroll
    for (int q = 0; q < 4; ++q) {
      int b = mt * 16 + rq + q;
      float gp = acc[mt][q] + xg[(t * 32 + b) * 2048 + wrow];
      int bl = (l & 48) | jj;
      float xi = __shfl(gp, bl);
      float xf = __shfl(gp, bl | 4);
      float xgg = __shfl(gp, bl | 8);
      float xo = __shfl(gp, bl | 12);
      float is = 1.f / (1.f + __expf(-xi));
      float fs = 1.f / (1.f + __expf(-xf));
      float e2 = __expf(2.f * xgg);
      float gt = 1.f - 2.f / (e2 + 1.f);       // tanh, inf-safe
      float os = 1.f / (1.f + __expf(-xo));
      float co = cbuf[b * 512 + j0 + jj];
      float cn = fs * co + is * gt;
      float e2c = __expf(2.f * cn);
      float hn = os * (1.f - 2.f / (e2c + 1.f));
      if ((l & 12) == 0) {  // gate-type 0 lanes do the unique write
        cbuf[b * 512 + j0 + jj] = cn;
        h_all[(b * 64 + t) * 512 + j0 + jj] = f2bf(hn);
      }
    }
  }
}

extern "C" void kernel_launch(void* const* d_in, const int* in_sizes, int n_in,
                              void* d_out, int out_size, void* d_ws, size_t ws_size,
                              hipStream_t stream) {
  (void)in_sizes; (void)n_in; (void)out_size; (void)ws_size;
  const float* iseq = (const float*)d_in[0];
  const float* h0   = (const float*)d_in[1];
  const float* wih  = (const float*)d_in[2];
  const float* whh  = (const float*)d_in[3];
  const float* bih  = (const float*)d_in[4];
  const float* bhh  = (const float*)d_in[5];
  const float* wout = (const float*)d_in[6];
  const float* bout = (const float*)d_in[7];

  char* ws = (char*)d_ws;
  u16* wout_bf = (u16*)(ws + 0);          // 32,768,000
  u16* wih_bf  = (u16*)(ws + 32768000);   // 2,097,152
  u16* whh_bf  = (u16*)(ws + 34865152);   // 2,097,152
  u16* ax      = (u16*)(ws + 36962304);   // 2,097,152
  u16* h_all   = (u16*)(ws + 39059456);   // 2,097,152
  u16* h0bf    = (u16*)(ws + 41156608);   // 32,768
  float* cbuf  = (float*)(ws + 41189376); // 65,536
  float* xg    = (float*)(ws + 41254912); // 16,777,216  (end 58,032,128)
  float* out   = (float*)d_out;

  prep_kernel<<<4096, 256, 0, stream>>>(iseq, h0, wih, whh, wout,
                                        wout_bf, wih_bf, whh_bf, ax, h0bf, cbuf);
  // x_gates = A_x @ W_ih^T + b_ih + b_hh   -> xg [2048][2048] f32
  gemm_bt<<<dim3(16, 16), 256, 0, stream>>>(ax, wih_bf, xg, bih, bhh, 2048);
  // 64 serial recurrence steps
  for (int t = 0; t < 64; ++t)
    lstm_step<<<128, 64, 0, stream>>>(whh_bf, xg, cbuf, h_all, h0bf, t);
  // logits = h_all @ W_out^T + b_out -> d_out [2048][32000] f32
  gemm_bt<<<dim3(250, 16), 256, 0, stream>>>(h_all, wout_bf, out, bout, nullptr, 32000);
}